// Round 1
// baseline (421.844 us; speedup 1.0000x reference)
//
#include <hip/hip_runtime.h>
#include <math.h>

#define NIMG 116          // 4*29 images
#define TW 118            // output tile width  (phase-1 columns = TW+10 = 128)
#define TH 16             // output tile height (strips of 8 rows, 2 strips)

// 11-tap Gaussian (size=11, sigma=1.5), fp32 values matching the reference.
static constexpr float W[11] = {
    0.00102838f, 0.00759876f, 0.03600078f, 0.10936075f, 0.21300554f,
    0.26601172f, 0.21300554f, 0.10936075f, 0.03600078f, 0.00759876f,
    0.00102838f};

__device__ __forceinline__ float frcp(float x) {
    return __builtin_amdgcn_rcpf(x);
}

__device__ __forceinline__ float fsig(float x) {
    float e = __builtin_amdgcn_exp2f(x * -1.4426950408889634f);
    return frcp(1.0f + e);
}

// One block per TWxTH output tile. Phase 1: batch-load 18 rows/thread into
// registers; a data-dependence keep-alive fence (asm volatile reading every
// loaded value) forces ALL 36 loads to be issued and materialized before any
// compute — R7 rocprof showed VGPR=56 with only sched_barrier, i.e. the
// scheduler was still sinking loads into the FMA loop and stalling on
// s_waitcnt per use (VALUBusy 80.8%, 19% idle). LDS caps occupancy at
// 4 blocks/CU so VGPR up to 128 is free. Then vertical Gaussian of
// {X,Y,XX,(YY),XY}; 2x2 pool computed AFTER the FMA loop from live registers.
// Phase 2: horizontal Gaussian from LDS via swizzled float4 reads + SSIM map.
// N, M are compile-time: folds 64-bit address chains (i*N) into shift-adds /
// immediates; at N<=64 every block takes the clamped path, which now folds
// min(x, N-1) + rc*N into cheap ops.
// SKIPYY: targets are binary (Y*Y==Y exactly) -> filter(YY)==filter(Y),
//         sigma2_sq = mu2 - mu2^2.
// NARROW: N <= 128 -> one x-tile covers all columns.
// NOTE: LDS padded to 40960 B regardless of Q. R4 measured that 32 KB ->
// 5 blocks/CU RAISES hbm traffic (FETCH 252->334 MB, WRITE 68->289 MB) and
// regresses 12%: locality beats occupancy here. Keep 4 blocks/CU.
template <int N, int M, bool SIG, bool POOL, bool SKIPYY, bool NARROW>
__global__ __launch_bounds__(256, 4)
void ssim_kernel(const float* __restrict__ X, const float* __restrict__ Y,
                 float* __restrict__ accSsim, float* __restrict__ accCs,
                 float* __restrict__ poolX, float* __restrict__ poolY) {
    constexpr int Q = SKIPYY ? 4 : 5;          // mu1, mu2, xx, (yy), xy
    __shared__ float smem[5 * 16 * 128];       // padded: 40960 B -> 4 blocks/CU

    const int tid = threadIdx.x;
    const int img = blockIdx.z;
    const int ox0 = NARROW ? 0 : blockIdx.x * TW;
    const int oy0 = blockIdx.y * TH;
    const long base = (long)img * N * N;

    // ================= phase 1: batch load ==================================
    const int c  = tid & 127;      // tile-local column 0..127
    const int s  = tid >> 7;       // strip 0/1 (rows 8s .. 8s+7 of v)
    const int ci = ox0 + c;        // global column
    constexpr int half = N >> 1;
    const int powned = NARROW ? N : min(TW, N - ox0);  // pool column ownership

    const float* __restrict__ Xb = X + base;
    const float* __restrict__ Yb = Y + base;

    // interior: no row/col clamping anywhere in this block (block-uniform)
    const bool interior = (oy0 + 25 < N) && (ox0 + 127 < N);

    float xv[18], yv[18];
    if (interior) {
        const float* __restrict__ xp = Xb + (long)(oy0 + 8 * s) * N + ci;
        const float* __restrict__ yp = Yb + (long)(oy0 + 8 * s) * N + ci;
#pragma unroll
        for (int i = 0; i < 18; i++) {
            xv[i] = xp[(long)i * N];
            yv[i] = yp[(long)i * N];
        }
    } else {
        const int cic = min(ci, N - 1);
#pragma unroll
        for (int i = 0; i < 18; i++) {
            int rc = min(oy0 + 8 * s + i, N - 1);
            xv[i] = Xb[(long)rc * N + cic];
            yv[i] = Yb[(long)rc * N + cic];
        }
    }
    // Data-dependence fence: force every loaded value into a VGPR HERE, so
    // all 36 loads are issued back-to-back and drained by one waitcnt.
    // (sched_barrier(0) alone did NOT achieve this — VGPR stayed at 56.)
    asm volatile("" ::
        "v"(xv[0]), "v"(xv[1]), "v"(xv[2]), "v"(xv[3]), "v"(xv[4]),
        "v"(xv[5]), "v"(xv[6]), "v"(xv[7]), "v"(xv[8]), "v"(xv[9]),
        "v"(xv[10]), "v"(xv[11]), "v"(xv[12]), "v"(xv[13]), "v"(xv[14]),
        "v"(xv[15]), "v"(xv[16]), "v"(xv[17]));
    asm volatile("" ::
        "v"(yv[0]), "v"(yv[1]), "v"(yv[2]), "v"(yv[3]), "v"(yv[4]),
        "v"(yv[5]), "v"(yv[6]), "v"(yv[7]), "v"(yv[8]), "v"(yv[9]),
        "v"(yv[10]), "v"(yv[11]), "v"(yv[12]), "v"(yv[13]), "v"(yv[14]),
        "v"(yv[15]), "v"(yv[16]), "v"(yv[17]));
    __builtin_amdgcn_sched_barrier(0);

    if (SIG) {
#pragma unroll
        for (int i = 0; i < 18; i++) xv[i] = fsig(xv[i]);
    }

    // ================= phase 1b: vertical filter ============================
    float a0[8], a1[8], a2[8], a4[8];
    float a3[SKIPYY ? 1 : 8];
#pragma unroll
    for (int o = 0; o < 8; o++) {
        a0[o] = a1[o] = a2[o] = a4[o] = 0.f;
        if constexpr (!SKIPYY) a3[o] = 0.f;
    }

#pragma unroll
    for (int i = 0; i < 18; i++) {
        float x = xv[i], y = yv[i];
        float xx = x * x, xy = x * y;
#pragma unroll
        for (int o = 0; o < 8; o++) {
            int t = i - o;
            if (t >= 0 && t < 11) {          // folds statically after unroll
                a0[o] = fmaf(W[t], x,  a0[o]);
                a1[o] = fmaf(W[t], y,  a1[o]);
                a2[o] = fmaf(W[t], xx, a2[o]);
                if constexpr (!SKIPYY) a3[o] = fmaf(W[t], y * y, a3[o]);
                a4[o] = fmaf(W[t], xy, a4[o]);
            }
        }
    }

    // ================= phase 1c: fused 2x2 pool (batched shuffles) ==========
    if (POOL) {
        float cx[4], cy[4];
#pragma unroll
        for (int p = 0; p < 4; p++) {
            cx[p] = xv[2 * p] + xv[2 * p + 1];
            cy[p] = yv[2 * p] + yv[2 * p + 1];
        }
#pragma unroll
        for (int p = 0; p < 4; p++) {
            float rx = __shfl_down(cx[p], 1, 64);   // column c+1 (same wave)
            float ry = __shfl_down(cy[p], 1, 64);
            if (!(c & 1) && c < powned) {
                int orow = (oy0 + 8 * s + 2 * p) >> 1;
                int ocol = ci >> 1;
                long pb = (long)img * half * half + (long)orow * half + ocol;
                poolX[pb] = 0.25f * (cx[p] + rx);
                poolY[pb] = 0.25f * (cy[p] + ry);
            }
        }
    }

    // store v to LDS, column-swizzled by 4*row to spread b128 read banks
#pragma unroll
    for (int o = 0; o < 8; o++) {
        int r = 8 * s + o;
        int cc = (c + 4 * r) & 127;
        smem[0 * 2048 + r * 128 + cc] = a0[o];
        smem[1 * 2048 + r * 128 + cc] = a1[o];
        smem[2 * 2048 + r * 128 + cc] = a2[o];
        if constexpr (!SKIPYY) smem[3 * 2048 + r * 128 + cc] = a3[o];
        smem[(Q - 1) * 2048 + r * 128 + cc] = a4[o];
    }
    __syncthreads();

    // ================= phase 2: horizontal filter + SSIM ====================
    const float C1 = 1e-4f, C2 = 9e-4f;
    float scs = 0.f, sss = 0.f;
    {
        const int r = tid >> 4;    // output row within tile
        const int k = tid & 15;    // 8-px column segment
        if (k < 15) {              // segment base 8k must be < 118
            float acc[Q][8];
#pragma unroll
            for (int q = 0; q < Q; q++) {
                float rg[20];
#pragma unroll
                for (int j5 = 0; j5 < 5; j5++) {
                    int col = (8 * k + 4 * j5 + 4 * r) & 127;   // swizzled chunk
                    const float4 v4 = *(const float4*)&smem[q * 2048 + r * 128 + col];
                    rg[4 * j5 + 0] = v4.x; rg[4 * j5 + 1] = v4.y;
                    rg[4 * j5 + 2] = v4.z; rg[4 * j5 + 3] = v4.w;
                }
#pragma unroll
                for (int j = 0; j < 8; j++) {
                    float a = 0.f;
#pragma unroll
                    for (int t = 0; t < 11; t++) a = fmaf(W[t], rg[j + t], a);
                    acc[q][j] = a;
                }
            }
            const int gy = oy0 + r;
            const bool rowok = gy < M;          // uniform per thread, hoisted
#pragma unroll
            for (int j = 0; j < 8; j++) {
                int lc = 8 * k + j;
                int gx = ox0 + lc;
                if (lc < TW && gx < M && rowok) {
                    float mu1 = acc[0][j], mu2 = acc[1][j];
                    float exx = acc[2][j], exy = acc[Q - 1][j];
                    float m11 = mu1 * mu1, m22 = mu2 * mu2, m12 = mu1 * mu2;
                    float s1 = exx - m11;
                    float s2 = SKIPYY ? (mu2 - m22) : (acc[3][j] - m22);
                    float s12 = exy - m12;
                    float cs = (2.f * s12 + C2) * frcp(s1 + s2 + C2);
                    float ssim = (2.f * m12 + C1) * frcp(m11 + m22 + C1) * cs;
                    scs += cs; sss += ssim;
                }
            }
        }
    }

    // block reduction (reuse smem after barrier)
    for (int off = 32; off > 0; off >>= 1) {
        scs += __shfl_down(scs, off, 64);
        sss += __shfl_down(sss, off, 64);
    }
    __syncthreads();
    int lane = tid & 63, wv = tid >> 6;
    if (lane == 0) { smem[wv] = scs; smem[4 + wv] = sss; }
    __syncthreads();
    if (tid == 0) {
        atomicAdd(&accCs[img],   smem[0] + smem[1] + smem[2] + smem[3]);
        atomicAdd(&accSsim[img], smem[4] + smem[5] + smem[6] + smem[7]);
    }
}

// acc layout: level l -> [l*2*NIMG .. +NIMG) ssim sums, [+NIMG .. +2*NIMG) cs sums
__global__ __launch_bounds__(128)
void finalize_kernel(const float* __restrict__ acc, float* __restrict__ out) {
    const float wts[5] = {0.0448f, 0.2856f, 0.3001f, 0.2363f, 0.1333f};
    const int Ms[5] = {502, 246, 118, 54, 22};
    int t = threadIdx.x;
    float v = 0.f;
    if (t < NIMG) {
        float prod = 1.f;
#pragma unroll
        for (int l = 0; l < 5; l++) {
            float inv = 1.0f / ((float)Ms[l] * (float)Ms[l]);
            float m = (l < 4) ? acc[l * 2 * NIMG + NIMG + t] * inv   // cs mean
                              : acc[l * 2 * NIMG + t] * inv;          // ssim mean
            m = fmaxf(m, 0.f);                                        // relu
            prod *= powf(m, wts[l]);
        }
        v = prod;
    }
    for (int off = 32; off > 0; off >>= 1) v += __shfl_down(v, off, 64);
    __shared__ float red[2];
    if ((t & 63) == 0) red[t >> 6] = v;
    __syncthreads();
    if (t == 0) out[0] = 1.0f - (red[0] + red[1]) / (float)NIMG;
}

extern "C" void kernel_launch(void* const* d_in, const int* in_sizes, int n_in,
                              void* d_out, int out_size, void* d_ws, size_t ws_size,
                              hipStream_t stream) {
    const float* logits = (const float*)d_in[0];
    const float* targets = (const float*)d_in[1];
    float* out = (float*)d_out;
    float* ws = (float*)d_ws;

    // workspace layout (floats)
    float* acc = ws;                               // 5*2*116 = 1160 floats
    size_t off = 1280;
    float* X1 = ws + off; off += (size_t)NIMG * 256 * 256;
    float* Y1 = ws + off; off += (size_t)NIMG * 256 * 256;
    float* X2 = ws + off; off += (size_t)NIMG * 128 * 128;
    float* Y2 = ws + off; off += (size_t)NIMG * 128 * 128;
    float* X3 = ws + off; off += (size_t)NIMG * 64 * 64;
    float* Y3 = ws + off; off += (size_t)NIMG * 64 * 64;
    float* X4 = ws + off; off += (size_t)NIMG * 32 * 32;
    float* Y4 = ws + off; off += (size_t)NIMG * 32 * 32;

    hipMemsetAsync(acc, 0, 1160 * sizeof(float), stream);

    // level 0: sigmoid + pool fused, binary targets -> SKIPYY
    {
        dim3 grid((512 + TW - 1) / TW, 512 / TH, NIMG);
        ssim_kernel<512, 502, true, true, true, false><<<grid, 256, 0, stream>>>(
            logits, targets, acc, acc + NIMG, X1, Y1);
    }
    // level 1: N=256, wide tiles
    {
        dim3 grid((256 + TW - 1) / TW, 256 / TH, NIMG);
        ssim_kernel<256, 246, false, true, false, false><<<grid, 256, 0, stream>>>(
            X1, Y1, acc + 2 * NIMG, acc + 3 * NIMG, X2, Y2);
    }
    // level 2: N=128, single x-tile
    {
        dim3 grid(1, 128 / TH, NIMG);
        ssim_kernel<128, 118, false, true, false, true><<<grid, 256, 0, stream>>>(
            X2, Y2, acc + 4 * NIMG, acc + 5 * NIMG, X3, Y3);
    }
    // level 3: N=64, single x-tile
    {
        dim3 grid(1, 64 / TH, NIMG);
        ssim_kernel<64, 54, false, true, false, true><<<grid, 256, 0, stream>>>(
            X3, Y3, acc + 6 * NIMG, acc + 7 * NIMG, X4, Y4);
    }
    // level 4: N=32, single x-tile, no pool
    {
        dim3 grid(1, 32 / TH, NIMG);
        ssim_kernel<32, 22, false, false, false, true><<<grid, 256, 0, stream>>>(
            X4, Y4, acc + 8 * NIMG, acc + 9 * NIMG, nullptr, nullptr);
    }

    finalize_kernel<<<1, 128, 0, stream>>>(acc, out);
}